// Round 3
// baseline (241.742 us; speedup 1.0000x reference)
//
#include <hip/hip_runtime.h>
#include <hip/hip_bf16.h>
#include <math.h>

#define BS    128
#define NC    1024
#define UNITS 512
#define FEAT  512
#define FOURU 2048
#define KG    8
#define NBLK  512   // must be co-resident: 256 thr, tiny LDS, <=2 blocks/CU needed

typedef short bf16x8 __attribute__((ext_vector_type(8)));
typedef float f32x4  __attribute__((ext_vector_type(4)));

// round-half-up bf16: |err| <= 0.5 ulp, 2 VALU ops
__device__ __forceinline__ unsigned short bf_rhu(float f) {
    union { float f; unsigned u; } v; v.f = f;
    return (unsigned short)((v.u + 0x8000u) >> 16);
}
__device__ __forceinline__ unsigned pack2(float a, float b) {
    return (unsigned)bf_rhu(a) | ((unsigned)bf_rhu(b) << 16);
}

// device-scope grid barrier (all NBLK blocks co-resident by construction)
__device__ __forceinline__ void gbar(unsigned* cnt, unsigned target) {
    __syncthreads();
    if (threadIdx.x == 0) {
        __threadfence();   // release all prior global writes
        __hip_atomic_fetch_add(cnt, 1u, __ATOMIC_ACQ_REL, __HIP_MEMORY_SCOPE_AGENT);
        while (__hip_atomic_load(cnt, __ATOMIC_ACQUIRE, __HIP_MEMORY_SCOPE_AGENT) < target)
            __builtin_amdgcn_s_sleep(8);
        __threadfence();   // acquire
    }
    __syncthreads();
}

__global__ __launch_bounds__(256, 2) void fused_kernel(
    const float* __restrict__ x, const float* __restrict__ logits,
    const float* __restrict__ h_st, const float* __restrict__ c_st,
    const float* __restrict__ kern, const float* __restrict__ reck,
    const float* __restrict__ bias,
    unsigned* __restrict__ bar, int* __restrict__ sidx,
    unsigned short* __restrict__ Abf,   // [128][1024] bf16
    unsigned short* __restrict__ Wt,    // [2048 n][1024 k] bf16
    float* __restrict__ z_part,         // [KG][128][2048] f32
    float* __restrict__ h_out, float* __restrict__ out_h, float* __restrict__ out_c)
{
    const int bid = blockIdx.x, t = threadIdx.x;
    const int wid = t >> 6, lane = t & 63, l15 = lane & 15, quad = lane >> 4;

    __shared__ int   s[BS];
    __shared__ float sv[4];
    __shared__ int   si[4];
    __shared__ int   sbi;

    // ================= phase 1 =================
    if (bid < BS) {
        // argmax of row b + build A row = [x_row | h_states[argmax]] in bf16
        int b = bid;
        float best = -INFINITY; int bi = 0;
        for (int i = t; i < NC; i += 256) {
            float v = logits[b * NC + i];
            if (v > best) { best = v; bi = i; }
        }
        for (int off = 32; off > 0; off >>= 1) {
            float ov = __shfl_down(best, off);
            int   oi = __shfl_down(bi, off);
            if (ov > best || (ov == best && oi < bi)) { best = ov; bi = oi; }
        }
        if ((t & 63) == 0) { sv[wid] = best; si[wid] = bi; }
        __syncthreads();
        if (t == 0) {
            for (int w = 1; w < 4; ++w)
                if (sv[w] > best || (sv[w] == best && si[w] < bi)) { best = sv[w]; bi = si[w]; }
            sidx[b] = bi;
            sbi = bi;
        }
        __syncthreads();
        int st = t & 127;
        const float* srcrow = (t < 128) ? (x + (long)b * FEAT)
                                        : (h_st + (long)sbi * UNITS);
        float4 v = *(const float4*)(srcrow + st * 4);
        unsigned lo = pack2(v.x, v.y), hi = pack2(v.z, v.w);
        unsigned du = (unsigned)b * 512u + (t < 128 ? 0u : 256u) + (unsigned)st * 2u;
        *(uint2*)((unsigned*)Abf + du) = make_uint2(lo, hi);
    } else {
        // transpose-convert weights: Wt[n][k], k<512 from kern, k>=512 from reck
        // wave-task = 64 consecutive n x one 8-k chunk; reads are 256-B coalesced
        int gw = (bid - BS) * 4 + wid;            // 0..1535
        for (int task = gw; task < 4096; task += 1536) {
            int kc = task >> 5;                   // 0..127
            int n  = (task & 31) * 64 + lane;
            int r0 = kc * 8;
            const float* base = (r0 < 512) ? (kern + (long)r0 * FOURU + n)
                                           : (reck + (long)(r0 - 512) * FOURU + n);
            bf16x8 o;
            #pragma unroll
            for (int j = 0; j < 8; ++j)
                o[j] = (short)bf_rhu(base[(long)j * FOURU]);
            *(bf16x8*)(Wt + (long)n * 1024 + r0) = o;
        }
    }
    gbar(bar, NBLK);

    // ================= phase 2: GEMM, no LDS, no barriers =================
    {
        int nt = bid & 63, kg = bid >> 6;
        int k0base = kg * 128 + quad * 8;
        f32x4 zero = {0.f, 0.f, 0.f, 0.f};
        f32x4 acc[2][2] = {{zero, zero}, {zero, zero}};
        #pragma unroll
        for (int kstep = 0; kstep < 4; ++kstep) {
            int k0 = k0base + kstep * 32;
            bf16x8 af[2], wf[2];
            #pragma unroll
            for (int ms = 0; ms < 2; ++ms) {
                int m = wid * 32 + ms * 16 + l15;
                af[ms] = *(const bf16x8*)(Abf + (long)m * 1024 + k0);
            }
            #pragma unroll
            for (int ns = 0; ns < 2; ++ns) {
                int n = nt * 32 + ns * 16 + l15;
                wf[ns] = *(const bf16x8*)(Wt + (long)n * 1024 + k0);
            }
            #pragma unroll
            for (int ms = 0; ms < 2; ++ms)
                #pragma unroll
                for (int ns = 0; ns < 2; ++ns)
                    acc[ms][ns] = __builtin_amdgcn_mfma_f32_16x16x32_bf16(
                                      af[ms], wf[ns], acc[ms][ns], 0, 0, 0);
        }
        // C/D layout: col = lane&15, row = quad*4 + reg
        float* zp = z_part + (long)kg * BS * FOURU;
        #pragma unroll
        for (int ms = 0; ms < 2; ++ms)
            #pragma unroll
            for (int ns = 0; ns < 2; ++ns)
                #pragma unroll
                for (int r = 0; r < 4; ++r) {
                    int m = wid * 32 + ms * 16 + quad * 4 + r;
                    int n = nt * 32 + ns * 16 + l15;
                    zp[(long)m * FOURU + n] = acc[ms][ns][r];
                }
    }
    gbar(bar + 1, NBLK);

    // ================= phase 3: fused LSTM + diff_scatter =================
    if (t < BS) s[t] = sidx[t];
    __syncthreads();
    float bi0 = bias[t],        bi1 = bias[256 + t];
    float bf0 = bias[512 + t],  bf1 = bias[768 + t];
    float bg0 = bias[1024 + t], bg1 = bias[1280 + t];
    float bo0 = bias[1536 + t], bo1 = bias[1792 + t];

    for (int jj = 0; jj < 2; ++jj) {
        int j = bid * 2 + jj;
        float ah0 = h_st[(long)j * UNITS + t], ah1 = h_st[(long)j * UNITS + 256 + t];
        float ac0 = c_st[(long)j * UNITS + t], ac1 = c_st[(long)j * UNITS + 256 + t];
        float mh0 = -INFINITY, mh1 = -INFINITY, mc0 = -INFINITY, mc1 = -INFINITY;
        int cnt = 0;
        for (int b = 0; b < BS; ++b) {
            if (s[b] == j) {                      // block-uniform branch
                ++cnt;
                float zi0 = bi0, zi1 = bi1, zf0 = bf0, zf1 = bf1;
                float zg0 = bg0, zg1 = bg1, zo0 = bo0, zo1 = bo1;
                #pragma unroll
                for (int g = 0; g < KG; ++g) {
                    const float* z = z_part + (long)g * BS * FOURU + (long)b * FOURU;
                    zi0 += z[t];        zi1 += z[256 + t];
                    zf0 += z[512 + t];  zf1 += z[768 + t];
                    zg0 += z[1024 + t]; zg1 += z[1280 + t];
                    zo0 += z[1536 + t]; zo1 += z[1792 + t];
                }
                float i0 = 1.f/(1.f+expf(-zi0)), i1 = 1.f/(1.f+expf(-zi1));
                float f0 = 1.f/(1.f+expf(-zf0)), f1 = 1.f/(1.f+expf(-zf1));
                float g0 = tanhf(zg0),           g1 = tanhf(zg1);
                float o0 = 1.f/(1.f+expf(-zo0)), o1 = 1.f/(1.f+expf(-zo1));
                float c0 = f0*ac0 + i0*g0,       c1 = f1*ac1 + i1*g1;
                float h0 = o0*tanhf(c0),         h1 = o1*tanhf(c1);
                h_out[(long)b * UNITS + t]       = h0;
                h_out[(long)b * UNITS + 256 + t] = h1;
                mh0 = fmaxf(mh0, h0); mh1 = fmaxf(mh1, h1);
                mc0 = fmaxf(mc0, c0); mc1 = fmaxf(mc1, c1);
            }
        }
        // count==BS: old state never in blend; count==0 -> old state
        out_h[(long)j * UNITS + t]       = (cnt == BS) ? mh0 : fmaxf(ah0, mh0);
        out_h[(long)j * UNITS + 256 + t] = (cnt == BS) ? mh1 : fmaxf(ah1, mh1);
        out_c[(long)j * UNITS + t]       = (cnt == BS) ? mc0 : fmaxf(ac0, mc0);
        out_c[(long)j * UNITS + 256 + t] = (cnt == BS) ? mc1 : fmaxf(ac1, mc1);
    }
}

extern "C" void kernel_launch(void* const* d_in, const int* in_sizes, int n_in,
                              void* d_out, int out_size, void* d_ws, size_t ws_size,
                              hipStream_t stream)
{
    (void)in_sizes; (void)n_in; (void)out_size; (void)ws_size;
    const float* x      = (const float*)d_in[0];
    const float* logits = (const float*)d_in[1];
    const float* h_st   = (const float*)d_in[2];
    const float* c_st   = (const float*)d_in[3];
    const float* kern   = (const float*)d_in[4];
    const float* reck   = (const float*)d_in[5];
    const float* bias   = (const float*)d_in[6];

    float* out        = (float*)d_out;
    float* out_h_step = out;                          // (128,512)
    float* out_newh   = out + BS * UNITS;             // (1024,512)
    float* out_newc   = out + BS * UNITS + NC * UNITS;

    char*           ws     = (char*)d_ws;
    unsigned*       bar    = (unsigned*)ws;                         // 8 B
    int*            sidx   = (int*)(ws + 256);                      // 512 B
    unsigned short* Abf    = (unsigned short*)(ws + 4096);          // 256 KB
    float*          z_part = (float*)(ws + (1u << 20));             // 8 MB
    unsigned short* Wt     = (unsigned short*)(ws + 10u * (1u << 20)); // 4 MB

    hipMemsetAsync(bar, 0, 2 * sizeof(unsigned), stream);
    fused_kernel<<<NBLK, 256, 0, stream>>>(x, logits, h_st, c_st, kern, reck, bias,
                                           bar, sidx, Abf, Wt, z_part,
                                           out_h_step, out_newh, out_newc);
}

// Round 4
// 111.138 us; speedup vs baseline: 2.1752x; 2.1752x over previous
//
#include <hip/hip_runtime.h>
#include <hip/hip_bf16.h>
#include <math.h>

#define BS    128
#define NC    1024
#define UNITS 512
#define FEAT  512
#define FOURU 2048
#define KG    4          // k-groups for the gemm split (1024/4 = 256 per group)
#define NT    32         // n-columns per gemm block
#define WPAD  40         // wst leading dim (80 B rows, 16B-aligned, 2-way max alias)

typedef short  bf16x8 __attribute__((ext_vector_type(8)));
typedef float  f32x4  __attribute__((ext_vector_type(4)));

// round-half-up bf16: |err| <= 0.5 ulp (same bound as RNE), 2 ops/elem
__device__ __forceinline__ unsigned short bf_rhu(float f) {
    union { float f; unsigned u; } v; v.f = f;
    return (unsigned short)((v.u + 0x8000u) >> 16);
}
__device__ __forceinline__ unsigned pack2(float a, float b) {
    return (unsigned)bf_rhu(a) | ((unsigned)bf_rhu(b) << 16);
}

// ---- K1: per-row argmax + build A_bf16 = [x | h_states[argmax]] ---------
__global__ __launch_bounds__(256) void argmax_prep_kernel(
    const float* __restrict__ logits, const float* __restrict__ x,
    const float* __restrict__ h_states,
    int* __restrict__ sidx, unsigned* __restrict__ Abf /* uint view, 512/row */)
{
    int b = blockIdx.x;
    int t = threadIdx.x;
    float best = -INFINITY; int bi = 0;
    for (int i = t; i < NC; i += 256) {
        float v = logits[b * NC + i];
        if (v > best) { best = v; bi = i; }
    }
    for (int off = 32; off > 0; off >>= 1) {
        float ov = __shfl_down(best, off);
        int   oi = __shfl_down(bi, off);
        if (ov > best || (ov == best && oi < bi)) { best = ov; bi = oi; }
    }
    __shared__ float sv[4]; __shared__ int si[4];
    __shared__ int sbi;
    int wid = t >> 6;
    if ((t & 63) == 0) { sv[wid] = best; si[wid] = bi; }
    __syncthreads();
    if (t == 0) {
        for (int w = 1; w < 4; ++w)
            if (sv[w] > best || (sv[w] == best && si[w] < bi)) { best = sv[w]; bi = si[w]; }
        sidx[b] = bi;
        sbi = bi;
    }
    __syncthreads();
    // convert: threads 0..127 -> x row, 128..255 -> gathered h row
    int st = t & 127;
    const float* srcrow = (t < 128) ? (x + (long)b * FEAT)
                                    : (h_states + (long)sbi * UNITS);
    float4 v = *(const float4*)(srcrow + st * 4);
    unsigned lo = pack2(v.x, v.y), hi = pack2(v.z, v.w);
    unsigned du = (unsigned)b * 512u + (t < 128 ? 0u : 256u) + (unsigned)st * 2u;
    *(uint2*)(Abf + du) = make_uint2(lo, hi);
}

// ---- K2: z_part[kg] = A_bf16[:, kslice] @ W[kslice, :] (bf16 MFMA) -------
// grid (64 n-tiles, 4 k-groups) = 256 blocks. Each block writes its own
// 128x32 f32 tile of z_part[kg]. No atomics, no memset dependency.
__global__ __launch_bounds__(256) void gemm_kernel(
    const unsigned short* __restrict__ Abf,   // [128][1024] bf16
    const float* __restrict__ kern, const float* __restrict__ reck,
    float* __restrict__ z_part)               // [KG][128][2048] f32
{
    // A tile stored as 16-B granules with XOR swizzle: granule(m, chunk p)
    // holds k-chunk c = (p ^ (m>>1)) & 3  -> frag reads are 2-way (free)
    __shared__ __align__(16) unsigned short as[BS * 32];    // 8 KB
    __shared__ __align__(16) unsigned short wst[NT * WPAD]; // [n][k] 2.5 KB

    int t = threadIdx.x;
    int ntile = blockIdx.x * NT;
    int kg = blockIdx.y;                      // 0..3
    const float* W = (kg < 2) ? kern : reck;
    int wk0base = (kg & 1) * 256;             // k offset inside the weight matrix
    int k0base  = kg * 256;                   // k offset inside A (1024 wide)

    int wid = t >> 6, lane = t & 63;
    int l15 = lane & 15, quad = lane >> 4;

    f32x4 zero = {0.f, 0.f, 0.f, 0.f};
    f32x4 acc[2][2] = {{zero, zero}, {zero, zero}};

    #pragma unroll
    for (int kstep = 0; kstep < 8; ++kstep) {
        int k0  = k0base  + kstep * 32;
        int wk0 = wk0base + kstep * 32;

        // stage A: 512 granules, 2 per thread, 16-B vector load + store
        for (int r = 0; r < 2; ++r) {
            int G = r * 256 + t;
            int m = G >> 2;
            int p = G & 3;
            int c = (p ^ (m >> 1)) & 3;
            bf16x8 v = *(const bf16x8*)(Abf + (long)m * 1024 + k0 + c * 8);
            *(bf16x8*)&as[G * 8] = v;
        }
        // stage W^T (f32 -> bf16): wst[n][kk]
        for (int p = 0; p < 4; ++p) {
            int kk = (t >> 5) + p * 8;
            int n  = t & 31;
            wst[n * WPAD + kk] = bf_rhu(W[(long)(wk0 + kk) * FOURU + ntile + n]);
        }
        __syncthreads();

        bf16x8 afrag[2], bfrag[2];
        for (int ms = 0; ms < 2; ++ms) {
            int m = wid * 32 + ms * 16 + l15;
            afrag[ms] = *(const bf16x8*)&as[(m * 4 + ((quad ^ (m >> 1)) & 3)) * 8];
        }
        for (int ns = 0; ns < 2; ++ns) {
            int n = ns * 16 + l15;
            bfrag[ns] = *(const bf16x8*)&wst[n * WPAD + quad * 8];
        }
        for (int ms = 0; ms < 2; ++ms)
            for (int ns = 0; ns < 2; ++ns)
                acc[ms][ns] = __builtin_amdgcn_mfma_f32_16x16x32_bf16(
                                  afrag[ms], bfrag[ns], acc[ms][ns], 0, 0, 0);
        __syncthreads();
    }

    // C/D layout: col = lane&15, row = quad*4 + reg
    float* zp = z_part + (long)kg * BS * FOURU;
    #pragma unroll
    for (int ms = 0; ms < 2; ++ms)
        #pragma unroll
        for (int ns = 0; ns < 2; ++ns)
            #pragma unroll
            for (int r = 0; r < 4; ++r) {
                int m = wid * 32 + ms * 16 + quad * 4 + r;
                int n = ntile + ns * 16 + l15;
                zp[(long)m * FOURU + n] = acc[ms][ns][r];
            }
}

// ---- K3: fused LSTM + diff_scatter --------------------------------------
// Block (j, u-half). Each row b belongs to exactly one class j = sidx[b], so
// the LSTM for (b,u) runs exactly once, inside the block owning class j.
__global__ __launch_bounds__(256) void scatter_lstm_kernel(
    const float* __restrict__ z_part, const float* __restrict__ bias,
    const float* __restrict__ h_states, const float* __restrict__ c_states,
    const int* __restrict__ sidx,
    float* __restrict__ h_out, float* __restrict__ out_h, float* __restrict__ out_c)
{
    __shared__ int s[BS];
    int t = threadIdx.x;
    if (t < BS) s[t] = sidx[t];
    __syncthreads();
    int j = blockIdx.x >> 1;
    int u = (blockIdx.x & 1) * 256 + t;

    float ah = h_states[(long)j * UNITS + u];
    float ac = c_states[(long)j * UNITS + u];   // == c0 for any matching b

    float mh = -INFINITY, mc = -INFINITY;
    int count = 0;
    float bi_ = bias[u], bf_ = bias[512 + u], bg_ = bias[1024 + u], bo_ = bias[1536 + u];

    for (int b = 0; b < BS; ++b) {
        if (s[b] == j) {                          // block-uniform branch
            ++count;
            float zi = bi_, zf = bf_, zg = bg_, zo = bo_;
            #pragma unroll
            for (int kg = 0; kg < KG; ++kg) {
                const float* zp = z_part + (long)kg * BS * FOURU + (long)b * FOURU;
                zi += zp[u];
                zf += zp[512 + u];
                zg += zp[1024 + u];
                zo += zp[1536 + u];
            }
            float ig = 1.f / (1.f + expf(-zi));
            float fg = 1.f / (1.f + expf(-zf));
            float gg = tanhf(zg);
            float og = 1.f / (1.f + expf(-zo));
            float c  = fg * ac + ig * gg;
            float h  = og * tanhf(c);
            h_out[(long)b * UNITS + u] = h;
            mh = fmaxf(mh, h);
            mc = fmaxf(mc, c);
        }
    }
    // count==BS: old state never appears in the blend; count==0 -> old state
    out_h[(long)j * UNITS + u] = (count == BS) ? mh : fmaxf(ah, mh);
    out_c[(long)j * UNITS + u] = (count == BS) ? mc : fmaxf(ac, mc);
}

extern "C" void kernel_launch(void* const* d_in, const int* in_sizes, int n_in,
                              void* d_out, int out_size, void* d_ws, size_t ws_size,
                              hipStream_t stream)
{
    (void)in_sizes; (void)n_in; (void)out_size; (void)ws_size;
    const float* x      = (const float*)d_in[0];
    const float* logits = (const float*)d_in[1];
    const float* h_st   = (const float*)d_in[2];
    const float* c_st   = (const float*)d_in[3];
    const float* kern   = (const float*)d_in[4];
    const float* reck   = (const float*)d_in[5];
    const float* bias   = (const float*)d_in[6];

    float* out        = (float*)d_out;
    float* out_h_step = out;                          // (128,512)
    float* out_newh   = out + BS * UNITS;             // (1024,512)
    float* out_newc   = out + BS * UNITS + NC * UNITS;

    char*     ws     = (char*)d_ws;
    int*      sidx   = (int*)ws;                               // 512 B
    unsigned* Abf    = (unsigned*)(ws + 1024);                 // 256 KB (bf16 view)
    float*    z_part = (float*)(ws + 1024 * 1024);             // 4 MB

    argmax_prep_kernel<<<BS, 256, 0, stream>>>(logits, x, h_st, sidx, Abf);
    gemm_kernel<<<dim3(FOURU / NT, KG), 256, 0, stream>>>(
        (const unsigned short*)Abf, kern, reck, z_part);
    scatter_lstm_kernel<<<NC * UNITS / 256, 256, 0, stream>>>(
        z_part, bias, h_st, c_st, sidx, out_h_step, out_newh, out_newc);
}

// Round 5
// 103.276 us; speedup vs baseline: 2.3407x; 1.0761x over previous
//
#include <hip/hip_runtime.h>
#include <hip/hip_bf16.h>
#include <math.h>

#define BS    128
#define NC    1024
#define UNITS 512
#define FEAT  512
#define FOURU 2048
#define KG    8          // k-groups for the gemm split (1024/8 = 128 per group)

typedef short bf16x8 __attribute__((ext_vector_type(8)));
typedef float f32x4  __attribute__((ext_vector_type(4)));

// round-half-up bf16: |err| <= 0.5 ulp (same bound as RNE), 2 VALU ops
__device__ __forceinline__ unsigned short bf_rhu(float f) {
    union { float f; unsigned u; } v; v.f = f;
    return (unsigned short)((v.u + 0x8000u) >> 16);
}
__device__ __forceinline__ unsigned pack2(float a, float b) {
    return (unsigned)bf_rhu(a) | ((unsigned)bf_rhu(b) << 16);
}

// ---- K1: prep. blocks 0..127: argmax + A_bf16 = [x | h_st[argmax]];
//          blocks 128..511: weights -> Wt[n][k] bf16 (transpose-convert).
__global__ __launch_bounds__(256) void prep_kernel(
    const float* __restrict__ logits, const float* __restrict__ x,
    const float* __restrict__ h_st,
    const float* __restrict__ kern, const float* __restrict__ reck,
    int* __restrict__ sidx,
    unsigned short* __restrict__ Abf,   // [128][1024] bf16
    unsigned short* __restrict__ Wt)    // [2048 n][1024 k] bf16
{
    const int bid = blockIdx.x, t = threadIdx.x;
    const int wid = t >> 6, lane = t & 63;

    if (bid < BS) {
        // per-row argmax of class_logits + build A row in bf16
        int b = bid;
        float best = -INFINITY; int bi = 0;
        for (int i = t; i < NC; i += 256) {
            float v = logits[b * NC + i];
            if (v > best) { best = v; bi = i; }
        }
        for (int off = 32; off > 0; off >>= 1) {
            float ov = __shfl_down(best, off);
            int   oi = __shfl_down(bi, off);
            if (ov > best || (ov == best && oi < bi)) { best = ov; bi = oi; }
        }
        __shared__ float sv[4]; __shared__ int si[4]; __shared__ int sbi;
        if ((t & 63) == 0) { sv[wid] = best; si[wid] = bi; }
        __syncthreads();
        if (t == 0) {
            for (int w = 1; w < 4; ++w)
                if (sv[w] > best || (sv[w] == best && si[w] < bi)) { best = sv[w]; bi = si[w]; }
            sidx[b] = bi;
            sbi = bi;
        }
        __syncthreads();
        int st = t & 127;
        const float* srcrow = (t < 128) ? (x + (long)b * FEAT)
                                        : (h_st + (long)sbi * UNITS);
        float4 v = *(const float4*)(srcrow + st * 4);
        unsigned lo = pack2(v.x, v.y), hi = pack2(v.z, v.w);
        unsigned du = (unsigned)b * 512u + (t < 128 ? 0u : 256u) + (unsigned)st * 2u;
        *(uint2*)((unsigned*)Abf + du) = make_uint2(lo, hi);
    } else {
        // Wt[n][k]: k<512 from kern, k>=512 from reck.
        // wave-task = 64 consecutive n x one 8-k chunk; reads 256-B coalesced
        int gw = (bid - BS) * 4 + wid;            // 0..1535
        for (int task = gw; task < 4096; task += 1536) {
            int kc = task >> 5;                   // 0..127
            int n  = (task & 31) * 64 + lane;
            int r0 = kc * 8;
            const float* base = (r0 < 512) ? (kern + (long)r0 * FOURU + n)
                                           : (reck + (long)(r0 - 512) * FOURU + n);
            bf16x8 o;
            #pragma unroll
            for (int j = 0; j < 8; ++j)
                o[j] = (short)bf_rhu(base[(long)j * FOURU]);
            *(bf16x8*)(Wt + (long)n * 1024 + r0) = o;
        }
    }
}

// ---- K2: z_part[kg] = A[:, ks] @ W[ks, :] -- zero LDS, zero barriers ----
// 512 blocks: nt = bid&63 (32-col n-tile), kg = bid>>6. Fragments straight
// from bf16 global; K-loop = 16 loads + 16 MFMAs, fully hoistable.
__global__ __launch_bounds__(256) void gemm_kernel(
    const unsigned short* __restrict__ Abf,   // [128][1024] bf16
    const unsigned short* __restrict__ Wt,    // [2048][1024] bf16
    float* __restrict__ z_part)               // [KG][128][2048] f32
{
    const int t = threadIdx.x;
    const int wid = t >> 6, lane = t & 63, l15 = lane & 15, quad = lane >> 4;
    const int nt = blockIdx.x & 63, kg = blockIdx.x >> 6;
    const int k0base = kg * 128 + quad * 8;

    f32x4 zero = {0.f, 0.f, 0.f, 0.f};
    f32x4 acc[2][2] = {{zero, zero}, {zero, zero}};

    #pragma unroll
    for (int kstep = 0; kstep < 4; ++kstep) {
        int k0 = k0base + kstep * 32;
        bf16x8 af[2], wf[2];
        #pragma unroll
        for (int ms = 0; ms < 2; ++ms) {
            int m = wid * 32 + ms * 16 + l15;
            af[ms] = *(const bf16x8*)(Abf + (long)m * 1024 + k0);
        }
        #pragma unroll
        for (int ns = 0; ns < 2; ++ns) {
            int n = nt * 32 + ns * 16 + l15;
            wf[ns] = *(const bf16x8*)(Wt + (long)n * 1024 + k0);
        }
        #pragma unroll
        for (int ms = 0; ms < 2; ++ms)
            #pragma unroll
            for (int ns = 0; ns < 2; ++ns)
                acc[ms][ns] = __builtin_amdgcn_mfma_f32_16x16x32_bf16(
                                  af[ms], wf[ns], acc[ms][ns], 0, 0, 0);
    }

    // C/D layout: col = lane&15, row = quad*4 + reg
    float* zp = z_part + (long)kg * BS * FOURU;
    #pragma unroll
    for (int ms = 0; ms < 2; ++ms)
        #pragma unroll
        for (int ns = 0; ns < 2; ++ns)
            #pragma unroll
            for (int r = 0; r < 4; ++r) {
                int m = wid * 32 + ms * 16 + quad * 4 + r;
                int n = nt * 32 + ns * 16 + l15;
                zp[(long)m * FOURU + n] = acc[ms][ns][r];
            }
}

// ---- K3: fused LSTM + diff_scatter (proven R2 version, KG=8) ------------
__global__ __launch_bounds__(256) void scatter_lstm_kernel(
    const float* __restrict__ z_part, const float* __restrict__ bias,
    const float* __restrict__ h_states, const float* __restrict__ c_states,
    const int* __restrict__ sidx,
    float* __restrict__ h_out, float* __restrict__ out_h, float* __restrict__ out_c)
{
    __shared__ int s[BS];
    int t = threadIdx.x;
    if (t < BS) s[t] = sidx[t];
    __syncthreads();
    int j = blockIdx.x >> 1;
    int u = (blockIdx.x & 1) * 256 + t;

    float ah = h_states[(long)j * UNITS + u];
    float ac = c_states[(long)j * UNITS + u];   // == c0 for any matching b

    float mh = -INFINITY, mc = -INFINITY;
    int count = 0;
    float bi_ = bias[u], bf_ = bias[512 + u], bg_ = bias[1024 + u], bo_ = bias[1536 + u];

    for (int b = 0; b < BS; ++b) {
        if (s[b] == j) {                          // block-uniform branch
            ++count;
            float zi = bi_, zf = bf_, zg = bg_, zo = bo_;
            #pragma unroll
            for (int kg = 0; kg < KG; ++kg) {
                const float* zp = z_part + (long)kg * BS * FOURU + (long)b * FOURU;
                zi += zp[u];
                zf += zp[512 + u];
                zg += zp[1024 + u];
                zo += zp[1536 + u];
            }
            float ig = 1.f / (1.f + expf(-zi));
            float fg = 1.f / (1.f + expf(-zf));
            float gg = tanhf(zg);
            float og = 1.f / (1.f + expf(-zo));
            float c  = fg * ac + ig * gg;
            float h  = og * tanhf(c);
            h_out[(long)b * UNITS + u] = h;
            mh = fmaxf(mh, h);
            mc = fmaxf(mc, c);
        }
    }
    // count==BS: old state never appears in the blend; count==0 -> old state
    out_h[(long)j * UNITS + u] = (count == BS) ? mh : fmaxf(ah, mh);
    out_c[(long)j * UNITS + u] = (count == BS) ? mc : fmaxf(ac, mc);
}

extern "C" void kernel_launch(void* const* d_in, const int* in_sizes, int n_in,
                              void* d_out, int out_size, void* d_ws, size_t ws_size,
                              hipStream_t stream)
{
    (void)in_sizes; (void)n_in; (void)out_size; (void)ws_size;
    const float* x      = (const float*)d_in[0];
    const float* logits = (const float*)d_in[1];
    const float* h_st   = (const float*)d_in[2];
    const float* c_st   = (const float*)d_in[3];
    const float* kern   = (const float*)d_in[4];
    const float* reck   = (const float*)d_in[5];
    const float* bias   = (const float*)d_in[6];

    float* out        = (float*)d_out;
    float* out_h_step = out;                          // (128,512)
    float* out_newh   = out + BS * UNITS;             // (1024,512)
    float* out_newc   = out + BS * UNITS + NC * UNITS;

    char*           ws     = (char*)d_ws;
    int*            sidx   = (int*)ws;                               // 512 B
    unsigned short* Abf    = (unsigned short*)(ws + 4096);           // 256 KB
    float*          z_part = (float*)(ws + (1u << 20));              // 8 MB
    unsigned short* Wt     = (unsigned short*)(ws + 10u * (1u << 20)); // 4 MB

    prep_kernel<<<512, 256, 0, stream>>>(logits, x, h_st, kern, reck, sidx, Abf, Wt);
    gemm_kernel<<<512, 256, 0, stream>>>(Abf, Wt, z_part);
    scatter_lstm_kernel<<<NC * UNITS / 256, 256, 0, stream>>>(
        z_part, bias, h_st, c_st, sidx, out_h_step, out_newh, out_newc);
}

// Round 6
// 102.614 us; speedup vs baseline: 2.3558x; 1.0065x over previous
//
#include <hip/hip_runtime.h>
#include <hip/hip_bf16.h>
#include <math.h>

#define BS    128
#define NC    1024
#define UNITS 512
#define FEAT  512
#define FOURU 2048
#define KG    4          // k-groups (1024/4 = 256 per group)
#define NT    16         // n-columns per gemm block -> grid (128, 4) = 512 blocks

typedef short bf16x8 __attribute__((ext_vector_type(8)));
typedef float f32x4  __attribute__((ext_vector_type(4)));

// round-half-up bf16: |err| <= 0.5 ulp (same bound as RNE), 2 VALU ops
__device__ __forceinline__ unsigned short bf_rhu(float f) {
    union { float f; unsigned u; } v; v.f = f;
    return (unsigned short)((v.u + 0x8000u) >> 16);
}
__device__ __forceinline__ unsigned pack2(float a, float b) {
    return (unsigned)bf_rhu(a) | ((unsigned)bf_rhu(b) << 16);
}

// ---- K1: per-row argmax + build A_bf16 = [x | h_states[argmax]] ---------
__global__ __launch_bounds__(256) void argmax_prep_kernel(
    const float* __restrict__ logits, const float* __restrict__ x,
    const float* __restrict__ h_states,
    int* __restrict__ sidx, unsigned* __restrict__ Abf /* uint view, 512/row */)
{
    int b = blockIdx.x;
    int t = threadIdx.x;
    float best = -INFINITY; int bi = 0;
    for (int i = t; i < NC; i += 256) {
        float v = logits[b * NC + i];
        if (v > best) { best = v; bi = i; }
    }
    for (int off = 32; off > 0; off >>= 1) {
        float ov = __shfl_down(best, off);
        int   oi = __shfl_down(bi, off);
        if (ov > best || (ov == best && oi < bi)) { best = ov; bi = oi; }
    }
    __shared__ float sv[4]; __shared__ int si[4]; __shared__ int sbi;
    int wid = t >> 6;
    if ((t & 63) == 0) { sv[wid] = best; si[wid] = bi; }
    __syncthreads();
    if (t == 0) {
        for (int w = 1; w < 4; ++w)
            if (sv[w] > best || (sv[w] == best && si[w] < bi)) { best = sv[w]; bi = si[w]; }
        sidx[b] = bi;
        sbi = bi;
    }
    __syncthreads();
    int st = t & 127;
    const float* srcrow = (t < 128) ? (x + (long)b * FEAT)
                                    : (h_states + (long)sbi * UNITS);
    float4 v = *(const float4*)(srcrow + st * 4);
    unsigned lo = pack2(v.x, v.y), hi = pack2(v.z, v.w);
    unsigned du = (unsigned)b * 512u + (t < 128 ? 0u : 256u) + (unsigned)st * 2u;
    *(uint2*)(Abf + du) = make_uint2(lo, hi);
}

// ---- K2: z_part[kg] = A[:, ks] @ W[ks, :] -- zero LDS, zero barriers ----
// grid (128 nt, 4 kg) = 512 blocks. A fragments from bf16 global (16-B
// loads); B fragments DIRECTLY from f32 weights (disjoint across blocks ->
// 8 MB read exactly once), converted in-register. No Wt intermediate.
__global__ __launch_bounds__(256) void gemm_kernel(
    const unsigned short* __restrict__ Abf,   // [128][1024] bf16
    const float* __restrict__ kern, const float* __restrict__ reck,
    float* __restrict__ z_part)               // [KG][128][2048] f32
{
    const int t = threadIdx.x;
    const int wid = t >> 6, lane = t & 63, l15 = lane & 15, quad = lane >> 4;
    const int nt = blockIdx.x, kg = blockIdx.y;
    const int n  = nt * NT + l15;
    const int k0base = kg * 256;                       // k offset inside A
    const float* W  = (kg < 2) ? kern : reck;
    const int wkbase = (kg & 1) * 256;                 // k offset inside W matrix

    f32x4 zero = {0.f, 0.f, 0.f, 0.f};
    f32x4 acc[2] = {zero, zero};

    #pragma unroll
    for (int kstep = 0; kstep < 8; ++kstep) {
        int k0  = k0base + kstep * 32 + quad * 8;
        int wk0 = wkbase + kstep * 32 + quad * 8;

        bf16x8 af[2], wf;
        #pragma unroll
        for (int ms = 0; ms < 2; ++ms) {
            int m = wid * 32 + ms * 16 + l15;
            af[ms] = *(const bf16x8*)(Abf + (long)m * 1024 + k0);
        }
        const float* Wp = W + (long)wk0 * FOURU + n;
        #pragma unroll
        for (int j = 0; j < 8; ++j)
            wf[j] = (short)bf_rhu(Wp[(long)j * FOURU]);

        #pragma unroll
        for (int ms = 0; ms < 2; ++ms)
            acc[ms] = __builtin_amdgcn_mfma_f32_16x16x32_bf16(af[ms], wf, acc[ms], 0, 0, 0);
    }

    // C/D layout: col = lane&15, row = quad*4 + reg
    float* zp = z_part + (long)kg * BS * FOURU;
    #pragma unroll
    for (int ms = 0; ms < 2; ++ms)
        #pragma unroll
        for (int r = 0; r < 4; ++r) {
            int m = wid * 32 + ms * 16 + quad * 4 + r;
            zp[(long)m * FOURU + n] = acc[ms][r];
        }
}

// ---- K3: fused LSTM + diff_scatter (KG=4) -------------------------------
__global__ __launch_bounds__(256) void scatter_lstm_kernel(
    const float* __restrict__ z_part, const float* __restrict__ bias,
    const float* __restrict__ h_states, const float* __restrict__ c_states,
    const int* __restrict__ sidx,
    float* __restrict__ h_out, float* __restrict__ out_h, float* __restrict__ out_c)
{
    __shared__ int s[BS];
    int t = threadIdx.x;
    if (t < BS) s[t] = sidx[t];
    __syncthreads();
    int j = blockIdx.x >> 1;
    int u = (blockIdx.x & 1) * 256 + t;

    float ah = h_states[(long)j * UNITS + u];
    float ac = c_states[(long)j * UNITS + u];   // == c0 for any matching b

    float mh = -INFINITY, mc = -INFINITY;
    int count = 0;
    float bi_ = bias[u], bf_ = bias[512 + u], bg_ = bias[1024 + u], bo_ = bias[1536 + u];

    for (int b = 0; b < BS; ++b) {
        if (s[b] == j) {                          // block-uniform branch
            ++count;
            float zi = bi_, zf = bf_, zg = bg_, zo = bo_;
            #pragma unroll
            for (int kg = 0; kg < KG; ++kg) {
                const float* zp = z_part + (long)kg * BS * FOURU + (long)b * FOURU;
                zi += zp[u];
                zf += zp[512 + u];
                zg += zp[1024 + u];
                zo += zp[1536 + u];
            }
            float ig = 1.f / (1.f + expf(-zi));
            float fg = 1.f / (1.f + expf(-zf));
            float gg = tanhf(zg);
            float og = 1.f / (1.f + expf(-zo));
            float c  = fg * ac + ig * gg;
            float h  = og * tanhf(c);
            h_out[(long)b * UNITS + u] = h;
            mh = fmaxf(mh, h);
            mc = fmaxf(mc, c);
        }
    }
    // count==BS: old state never appears in the blend; count==0 -> old state
    out_h[(long)j * UNITS + u] = (count == BS) ? mh : fmaxf(ah, mh);
    out_c[(long)j * UNITS + u] = (count == BS) ? mc : fmaxf(ac, mc);
}

extern "C" void kernel_launch(void* const* d_in, const int* in_sizes, int n_in,
                              void* d_out, int out_size, void* d_ws, size_t ws_size,
                              hipStream_t stream)
{
    (void)in_sizes; (void)n_in; (void)out_size; (void)ws_size;
    const float* x      = (const float*)d_in[0];
    const float* logits = (const float*)d_in[1];
    const float* h_st   = (const float*)d_in[2];
    const float* c_st   = (const float*)d_in[3];
    const float* kern   = (const float*)d_in[4];
    const float* reck   = (const float*)d_in[5];
    const float* bias   = (const float*)d_in[6];

    float* out        = (float*)d_out;
    float* out_h_step = out;                          // (128,512)
    float* out_newh   = out + BS * UNITS;             // (1024,512)
    float* out_newc   = out + BS * UNITS + NC * UNITS;

    char*           ws     = (char*)d_ws;
    int*            sidx   = (int*)ws;                    // 512 B
    unsigned*       Abf    = (unsigned*)(ws + 4096);      // 256 KB (uint view)
    float*          z_part = (float*)(ws + (1u << 20));   // 4 MB

    argmax_prep_kernel<<<BS, 256, 0, stream>>>(logits, x, h_st, sidx, Abf);
    gemm_kernel<<<dim3(128, KG), 256, 0, stream>>>(
        (const unsigned short*)Abf, kern, reck, z_part);
    scatter_lstm_kernel<<<NC * UNITS / 256, 256, 0, stream>>>(
        z_part, bias, h_st, c_st, sidx, out_h_step, out_newh, out_newc);
}